// Round 2
// baseline (77381.836 us; speedup 1.0000x reference)
//
#include <hip/hip_runtime.h>

// Fused 2-layer LSTM + MLP head with output feedback.
// Persistent cooperative kernel: 256 blocks x 256 threads, 3 grid barriers/step.
// fp32 everywhere (correctness baseline). States c1/c2 live in registers.
// h1/h2 broadcast through the d_out hs1/hs2 chunks themselves.

#define NN   256
#define LL   256
#define HINN 64
#define H1   512
#define H2   256
#define LH   (LL * H1)            // 131072

#define OFF_HS1 65536L
#define OFF_CS1 (OFF_HS1 + 33554432L)
#define OFF_HS2 (OFF_CS1 + 33554432L)
#define OFF_CS2 (OFF_HS2 + 33554432L)

struct P {
  const float *x, *Wih1, *Whh1, *bih1, *bhh1,
              *Wih2, *Whh2, *bih2, *bhh2,
              *W1, *b1, *W2, *b2;
  float *out, *ws;
};

__global__ void ws_init(float* ws) {
  for (int i = threadIdx.x; i < 640; i += 256) ws[i] = 0.f;
}

__device__ __forceinline__ float sigf(float x)   { return 1.0f / (1.0f + __expf(-x)); }
__device__ __forceinline__ float tanhf_(float x) { return 2.0f / (1.0f + __expf(-2.0f * x)) - 1.0f; }

__device__ __forceinline__ void fma4(float& a, const float4 h, const float4 w) {
  a = fmaf(h.x, w.x, a); a = fmaf(h.y, w.y, a);
  a = fmaf(h.z, w.z, a); a = fmaf(h.w, w.w, a);
}

template<bool WVEC>
__device__ __forceinline__ float4 ldw4(const float* p) {
  if constexpr (WVEC) {
    return *(const float4*)p;
  } else {                 // W_ih1 rows have stride 65 -> not 16B aligned
    float4 v; v.x = p[0]; v.y = p[1]; v.z = p[2]; v.w = p[3]; return v;
  }
}

// acc[4 rows][2 gates] += h[rows, k] * w[gates, k], rows = tr + {0,16,32,48}
template<bool WVEC>
__device__ __forceinline__ void gemm_acc(
    float (&acc)[4][2],
    const float* __restrict__ hbase, long hstr,
    const float* __restrict__ w0, const float* __restrict__ w1,
    int K, int tr)
{
  const float* __restrict__ hp0 = hbase + (long)(tr     ) * hstr;
  const float* __restrict__ hp1 = hbase + (long)(tr + 16) * hstr;
  const float* __restrict__ hp2 = hbase + (long)(tr + 32) * hstr;
  const float* __restrict__ hp3 = hbase + (long)(tr + 48) * hstr;
  #pragma unroll 4
  for (int k = 0; k < K; k += 4) {
    float4 wv0 = ldw4<WVEC>(w0 + k);
    float4 wv1 = ldw4<WVEC>(w1 + k);
    float4 h0 = *(const float4*)(hp0 + k);
    float4 h1 = *(const float4*)(hp1 + k);
    float4 h2 = *(const float4*)(hp2 + k);
    float4 h3 = *(const float4*)(hp3 + k);
    fma4(acc[0][0], h0, wv0); fma4(acc[0][1], h0, wv1);
    fma4(acc[1][0], h1, wv0); fma4(acc[1][1], h1, wv1);
    fma4(acc[2][0], h2, wv0); fma4(acc[2][1], h2, wv1);
    fma4(acc[3][0], h3, wv0); fma4(acc[3][1], h3, wv1);
  }
}

// Grid barrier: bar[0]=arrive counter, bar[16]=generation. 256 blocks.
__device__ __forceinline__ void gbar(unsigned* bar) {
  __syncthreads();
  if (threadIdx.x == 0) {
    unsigned gen = __hip_atomic_load(bar + 16, __ATOMIC_SEQ_CST, __HIP_MEMORY_SCOPE_AGENT);
    unsigned arr = __hip_atomic_fetch_add(bar, 1u, __ATOMIC_SEQ_CST, __HIP_MEMORY_SCOPE_AGENT);
    if (arr == 255u) {
      __hip_atomic_store(bar, 0u, __ATOMIC_SEQ_CST, __HIP_MEMORY_SCOPE_AGENT);
      __hip_atomic_fetch_add(bar + 16, 1u, __ATOMIC_SEQ_CST, __HIP_MEMORY_SCOPE_AGENT);
    } else {
      while (__hip_atomic_load(bar + 16, __ATOMIC_SEQ_CST, __HIP_MEMORY_SCOPE_AGENT) == gen)
        __builtin_amdgcn_s_sleep(1);
    }
  }
  __syncthreads();
}

// gate exchange -> i,f,g,o -> c,h update -> store to output chunks
__device__ __forceinline__ void lstm_update_store(
    float (&acc)[4][2], float (&c)[2],
    float* dout, long offH, long offC,
    int r0, int u0, int t, int tid, float (*sG)[34])
{
  const int tr = tid & 15, tg = (tid >> 4) << 1;
  #pragma unroll
  for (int rr = 0; rr < 4; ++rr) {
    sG[tr + (rr << 4)][tg    ] = acc[rr][0];
    sG[tr + (rr << 4)][tg + 1] = acc[rr][1];
  }
  __syncthreads();
  #pragma unroll
  for (int p2 = 0; p2 < 2; ++p2) {
    const int idx = tid + (p2 << 8);
    const int r = idx >> 3, uu = idx & 7;
    const float gi = sG[r][uu], gf = sG[r][8 + uu],
                gc = sG[r][16 + uu], go = sG[r][24 + uu];
    const float cn = fmaf(sigf(gf), c[p2], sigf(gi) * tanhf_(gc));
    const float hn = sigf(go) * tanhf_(cn);
    c[p2] = cn;
    const long base = (long)(r0 + r) * LH + (long)t * H1 + (u0 + uu);
    dout[offH + base] = hn;
    dout[offC + base] = cn;
  }
}

__global__ void __launch_bounds__(256, 1) lstm_fused(P p) {
  const int b = blockIdx.x, tid = threadIdx.x;
  // S1/S2 mapping: 4 batch tiles (64 rows) x 64 unit tiles (8 hidden units)
  const int i1 = b >> 6, j1 = b & 63;
  const int r0 = i1 << 6, u0 = j1 << 3;
  const int tr = tid & 15, tg = (tid >> 4) << 1;
  const int g0 = ((tg    ) >> 3) * 512 + u0 + ((tg    ) & 7);  // global gate rows
  const int g1 = ((tg + 1) >> 3) * 512 + u0 + ((tg + 1) & 7);
  // S3 mapping: 16 batch tiles (16 rows) x 16 H2 tiles (16 units)
  const int i3 = b >> 4, j3 = b & 15;
  const int r3 = i3 << 4, m0 = j3 << 4;
  const int rS = tid & 15, mS = tid >> 4;

  unsigned* bar = (unsigned*)p.ws;
  float* outacc = p.ws + 64;      // [2][256], parity-alternating out accumulator

  __shared__ float sG[64][34];
  __shared__ float sR[16][17];

  float c1[2] = {0.f, 0.f}, c2[2] = {0.f, 0.f};

  const float bias1_0 = p.bih1[g0] + p.bhh1[g0];
  const float bias1_1 = p.bih1[g1] + p.bhh1[g1];
  const float bias2_0 = p.bih2[g0] + p.bhh2[g0];
  const float bias2_1 = p.bih2[g1] + p.bhh2[g1];
  const float w65_0 = p.Wih1[(long)g0 * 65 + 64];   // prev-output column
  const float w65_1 = p.Wih1[(long)g1 * 65 + 64];
  const float b1v = p.b1[m0 + mS];
  const float w2v = p.W2[m0 + mS];
  const float b2v = p.b2[0];

  for (int t = 0; t < LL; ++t) {
    // ---------------- S1: LSTM layer 1 ----------------
    {
      if (t > 0 && j1 == 0 && tid < 64)   // publish out(t-1)
        p.out[(long)(r0 + tid) * LL + (t - 1)] =
            outacc[(((t - 1) & 1) << 8) + r0 + tid] + b2v;

      float acc[4][2];
      acc[0][0] = bias1_0; acc[1][0] = bias1_0; acc[2][0] = bias1_0; acc[3][0] = bias1_0;
      acc[0][1] = bias1_1; acc[1][1] = bias1_1; acc[2][1] = bias1_1; acc[3][1] = bias1_1;

      // x part (K=64)
      gemm_acc<false>(acc, p.x + ((long)r0 * LL + t) * HINN, (long)LL * HINN,
                      p.Wih1 + (long)g0 * 65, p.Wih1 + (long)g1 * 65, HINN, tr);
      if (t > 0) {
        // prev-output rank-1 term
        #pragma unroll
        for (int rr = 0; rr < 4; ++rr) {
          const float pv = outacc[(((t - 1) & 1) << 8) + r0 + tr + (rr << 4)] + b2v;
          acc[rr][0] = fmaf(pv, w65_0, acc[rr][0]);
          acc[rr][1] = fmaf(pv, w65_1, acc[rr][1]);
        }
        // W_hh1 @ h1(t-1) (K=512), h1 read from hs1 output chunk
        gemm_acc<true>(acc, p.out + OFF_HS1 + (long)r0 * LH + (long)(t - 1) * H1, LH,
                       p.Whh1 + (long)g0 * H1, p.Whh1 + (long)g1 * H1, H1, tr);
      }
      lstm_update_store(acc, c1, p.out, OFF_HS1, OFF_CS1, r0, u0, t, tid, sG);
    }
    gbar(bar);
    // ---------------- S2: LSTM layer 2 ----------------
    {
      if (b == 0) outacc[(((t + 1) & 1) << 8) + tid] = 0.f;  // pre-zero next accum

      float acc[4][2];
      acc[0][0] = bias2_0; acc[1][0] = bias2_0; acc[2][0] = bias2_0; acc[3][0] = bias2_0;
      acc[0][1] = bias2_1; acc[1][1] = bias2_1; acc[2][1] = bias2_1; acc[3][1] = bias2_1;

      gemm_acc<true>(acc, p.out + OFF_HS1 + (long)r0 * LH + (long)t * H1, LH,
                     p.Wih2 + (long)g0 * H1, p.Wih2 + (long)g1 * H1, H1, tr);
      if (t > 0)
        gemm_acc<true>(acc, p.out + OFF_HS2 + (long)r0 * LH + (long)(t - 1) * H1, LH,
                       p.Whh2 + (long)g0 * H1, p.Whh2 + (long)g1 * H1, H1, tr);

      lstm_update_store(acc, c2, p.out, OFF_HS2, OFF_CS2, r0, u0, t, tid, sG);
    }
    gbar(bar);
    // ---------------- S3: MLP head ----------------
    {
      float a = b1v;
      const float* hrow = p.out + OFF_HS2 + (long)(r3 + rS) * LH + (long)t * H1;
      const float* wrow = p.W1 + (long)(m0 + mS) * H1;
      #pragma unroll 4
      for (int k = 0; k < H1; k += 4) {
        float4 hv = *(const float4*)(hrow + k);
        float4 wv = *(const float4*)(wrow + k);
        fma4(a, hv, wv);
      }
      const float z = fmaxf(a, 0.f) * w2v;     // relu(z) * W2[m]
      sR[mS][rS] = z;
      __syncthreads();
      if (tid < 16) {
        float s = 0.f;
        #pragma unroll
        for (int m = 0; m < 16; ++m) s += sR[m][tid];
        atomicAdd(outacc + ((t & 1) << 8) + r3 + tid, s);
      }
    }
    gbar(bar);
  }
  // publish out(255)
  if (j1 == 0 && tid < 64)
    p.out[(long)(r0 + tid) * LL + 255] = outacc[(1 << 8) + r0 + tid] + b2v;
}

extern "C" void kernel_launch(void* const* d_in, const int* in_sizes, int n_in,
                              void* d_out, int out_size, void* d_ws, size_t ws_size,
                              hipStream_t stream) {
  P prm;
  prm.x    = (const float*)d_in[0];
  prm.Wih1 = (const float*)d_in[1];
  prm.Whh1 = (const float*)d_in[2];
  prm.bih1 = (const float*)d_in[3];
  prm.bhh1 = (const float*)d_in[4];
  prm.Wih2 = (const float*)d_in[5];
  prm.Whh2 = (const float*)d_in[6];
  prm.bih2 = (const float*)d_in[7];
  prm.bhh2 = (const float*)d_in[8];
  prm.W1   = (const float*)d_in[9];
  prm.b1   = (const float*)d_in[10];
  prm.W2   = (const float*)d_in[11];
  prm.b2   = (const float*)d_in[12];
  prm.out  = (float*)d_out;
  prm.ws   = (float*)d_ws;

  hipLaunchKernelGGL(ws_init, dim3(1), dim3(256), 0, stream, prm.ws);

  void* kargs[] = { (void*)&prm };
  hipError_t err = hipLaunchCooperativeKernel((const void*)lstm_fused,
                                              dim3(256), dim3(256), kargs, 0, stream);
  if (err != hipSuccess) {
    // fallback: 256 blocks on 256 CUs are trivially co-resident
    hipLaunchKernelGGL(lstm_fused, dim3(256), dim3(256), 0, stream, prm);
  }
}